// Round 1
// baseline (7151.965 us; speedup 1.0000x reference)
//
#include <hip/hip_runtime.h>

// GCN 3-layer. Math per layer (input u, weight W, bias b):
//   z_i = u_i * dinv_i                      (scatter payload)
//   s_i = sum_{e: dst=i} z_{src_e}          (atomic scatter)
//   out_i = (dinv_i * (s_i + z_i)) @ W + b  (self-loop folds into s+z)
// Layer 1 scatters pre-W (2ch), layer 2 (4ch), layer 3 post-W (2ch).

#define N_THREADS 256

__global__ void zero_kernel(float* p, int n4) {
    int i = blockIdx.x * blockDim.x + threadIdx.x;
    if (i < n4) ((float4*)p)[i] = make_float4(0.f, 0.f, 0.f, 0.f);
}

__global__ void deg_kernel(const int* __restrict__ dst, float* __restrict__ deg, int E) {
    int e = blockIdx.x * blockDim.x + threadIdx.x;
    if (e < E) unsafeAtomicAdd(&deg[dst[e]], 1.0f);
}

// dinv = rsqrt(deg+1); z1 = x * dinv  (2ch)
__global__ void node1_kernel(const float* __restrict__ x, const float* __restrict__ deg,
                             float* __restrict__ dinv, float* __restrict__ z1, int N) {
    int i = blockIdx.x * blockDim.x + threadIdx.x;
    if (i < N) {
        float di = rsqrtf(deg[i] + 1.0f);
        dinv[i] = di;
        float2 xv = ((const float2*)x)[i];
        ((float2*)z1)[i] = make_float2(xv.x * di, xv.y * di);
    }
}

__global__ void edge2_kernel(const int* __restrict__ src, const int* __restrict__ dst,
                             const float* __restrict__ z, float* __restrict__ s, int E) {
    int e = blockIdx.x * blockDim.x + threadIdx.x;
    if (e < E) {
        int u = src[e], v = dst[e];
        float2 zv = ((const float2*)z)[u];
        unsafeAtomicAdd(&s[2 * v + 0], zv.x);
        unsafeAtomicAdd(&s[2 * v + 1], zv.y);
    }
}

__global__ void edge4_kernel(const int* __restrict__ src, const int* __restrict__ dst,
                             const float* __restrict__ z, float* __restrict__ s, int E) {
    int e = blockIdx.x * blockDim.x + threadIdx.x;
    if (e < E) {
        int u = src[e], v = dst[e];
        float4 zv = ((const float4*)z)[u];
        unsafeAtomicAdd(&s[4 * v + 0], zv.x);
        unsafeAtomicAdd(&s[4 * v + 1], zv.y);
        unsafeAtomicAdd(&s[4 * v + 2], zv.z);
        unsafeAtomicAdd(&s[4 * v + 3], zv.w);
    }
}

// g(2) = dinv*(s1+z1); h1(4) = tanh(g@W1 + b1); z2 = h1*dinv
__global__ void node2_kernel(const float* __restrict__ dinv, const float* __restrict__ s1,
                             const float* __restrict__ z1,
                             const float* __restrict__ W1, const float* __restrict__ b1,
                             float* __restrict__ z2, int N) {
    int i = blockIdx.x * blockDim.x + threadIdx.x;
    if (i < N) {
        float di = dinv[i];
        float2 sv = ((const float2*)s1)[i];
        float2 zv = ((const float2*)z1)[i];
        float g0 = di * (sv.x + zv.x);
        float g1 = di * (sv.y + zv.y);
        float4 o;
        o.x = di * tanhf(g0 * W1[0] + g1 * W1[4] + b1[0]);
        o.y = di * tanhf(g0 * W1[1] + g1 * W1[5] + b1[1]);
        o.z = di * tanhf(g0 * W1[2] + g1 * W1[6] + b1[2]);
        o.w = di * tanhf(g0 * W1[3] + g1 * W1[7] + b1[3]);
        ((float4*)z2)[i] = o;
    }
}

// g(4) = dinv*(s2+z2); h2(4) = tanh(g@W2 + b2); z3(2) = (h2@W3)*dinv
__global__ void node3_kernel(const float* __restrict__ dinv, const float* __restrict__ s2,
                             const float* __restrict__ z2,
                             const float* __restrict__ W2, const float* __restrict__ b2,
                             const float* __restrict__ W3,
                             float* __restrict__ z3, int N) {
    int i = blockIdx.x * blockDim.x + threadIdx.x;
    if (i < N) {
        float di = dinv[i];
        float4 sv = ((const float4*)s2)[i];
        float4 zv = ((const float4*)z2)[i];
        float g[4] = { di * (sv.x + zv.x), di * (sv.y + zv.y),
                       di * (sv.z + zv.z), di * (sv.w + zv.w) };
        float h[4];
        #pragma unroll
        for (int c = 0; c < 4; ++c) {
            float acc = b2[c];
            #pragma unroll
            for (int k = 0; k < 4; ++k) acc += g[k] * W2[4 * k + c];
            h[c] = tanhf(acc);
        }
        float v0 = 0.f, v1 = 0.f;
        #pragma unroll
        for (int k = 0; k < 4; ++k) {
            v0 += h[k] * W3[2 * k + 0];
            v1 += h[k] * W3[2 * k + 1];
        }
        ((float2*)z3)[i] = make_float2(v0 * di, v1 * di);
    }
}

// out = dinv*(s3+z3) + b3
__global__ void node4_kernel(const float* __restrict__ dinv, const float* __restrict__ s3,
                             const float* __restrict__ z3, const float* __restrict__ b3,
                             float* __restrict__ out, int N) {
    int i = blockIdx.x * blockDim.x + threadIdx.x;
    if (i < N) {
        float di = dinv[i];
        float2 sv = ((const float2*)s3)[i];
        float2 zv = ((const float2*)z3)[i];
        ((float2*)out)[i] = make_float2(di * (sv.x + zv.x) + b3[0],
                                        di * (sv.y + zv.y) + b3[1]);
    }
}

extern "C" void kernel_launch(void* const* d_in, const int* in_sizes, int n_in,
                              void* d_out, int out_size, void* d_ws, size_t ws_size,
                              hipStream_t stream) {
    const float* x   = (const float*)d_in[0];
    const int*   ei  = (const int*)d_in[1];
    const float* W1  = (const float*)d_in[2];
    const float* b1  = (const float*)d_in[3];
    const float* W2  = (const float*)d_in[4];
    const float* b2  = (const float*)d_in[5];
    const float* W3  = (const float*)d_in[6];
    const float* b3  = (const float*)d_in[7];
    float* out = (float*)d_out;

    const int N = in_sizes[0] / 2;
    const int E = in_sizes[1] / 2;
    const int* src = ei;
    const int* dst = ei + E;

    // ws layout (floats): [deg .5M][s1 1M][s2 2M][s3 1M][dinv .5M][z1 1M][z2 2M][z3 1M]
    float* ws   = (float*)d_ws;
    float* deg  = ws;
    float* s1   = ws + (size_t)N;          // N*2
    float* s2   = s1 + (size_t)2 * N;      // N*4
    float* s3   = s2 + (size_t)4 * N;      // N*2
    float* dinv = s3 + (size_t)2 * N;      // N
    float* z1   = dinv + (size_t)N;        // N*2
    float* z2   = z1 + (size_t)2 * N;      // N*4
    float* z3   = z2 + (size_t)4 * N;      // N*2

    const int zeroN = 9 * N;               // deg + s1 + s2 + s3 = 9N floats
    const int zero4 = zeroN / 4;

    dim3 blk(N_THREADS);
    dim3 gE((E + N_THREADS - 1) / N_THREADS);
    dim3 gN((N + N_THREADS - 1) / N_THREADS);
    dim3 gZ((zero4 + N_THREADS - 1) / N_THREADS);

    zero_kernel<<<gZ, blk, 0, stream>>>(ws, zero4);
    deg_kernel<<<gE, blk, 0, stream>>>(dst, deg, E);
    node1_kernel<<<gN, blk, 0, stream>>>(x, deg, dinv, z1, N);
    edge2_kernel<<<gE, blk, 0, stream>>>(src, dst, z1, s1, E);
    node2_kernel<<<gN, blk, 0, stream>>>(dinv, s1, z1, W1, b1, z2, N);
    edge4_kernel<<<gE, blk, 0, stream>>>(src, dst, z2, s2, E);
    node3_kernel<<<gN, blk, 0, stream>>>(dinv, s2, z2, W2, b2, W3, z3, N);
    edge2_kernel<<<gE, blk, 0, stream>>>(src, dst, z3, s3, E);
    node4_kernel<<<gN, blk, 0, stream>>>(dinv, s3, z3, b3, out, N);
}

// Round 2
// 2241.197 us; speedup vs baseline: 3.1911x; 3.1911x over previous
//
#include <hip/hip_runtime.h>

// GCN 3-layer via CSR gather (no fp32 atomics).
// Per layer (input u): z = u*dinv; s_i = sum_{e:dst=i} z[src_e];
//   out_i = (dinv_i*(s_i + z_i)) @ W + b   (self-loop folds into s+z).
// Build: rank_e = atomicAdd(cnt[dst_e],1) (int, with return), pk_e = src|rank<<19;
//   rowptr = exscan(cnt); csr[rowptr[dst]+rank] = src  (no atomics in fill).
// Layers gather from csr — zero atomics, cache-resident z tables.

#define TPB 256

__global__ void zero_int(int* p, int n) {
    int i = blockIdx.x * blockDim.x + threadIdx.x;
    if (i < n) p[i] = 0;
}

// pk path: count + store packed (src | rank<<19). N < 2^19, rank < 2^13.
__global__ void count_rank(const int* __restrict__ dst, const int* __restrict__ src,
                           int* __restrict__ cnt, unsigned* __restrict__ pk, int E) {
    int e = blockIdx.x * blockDim.x + threadIdx.x;
    if (e < E) {
        int v = dst[e];
        int r = atomicAdd(&cnt[v], 1);
        pk[e] = (unsigned)src[e] | ((unsigned)r << 19);
    }
}

// cursor path: count only
__global__ void count_only(const int* __restrict__ dst, int* __restrict__ cnt, int E) {
    int e = blockIdx.x * blockDim.x + threadIdx.x;
    if (e < E) atomicAdd(&cnt[dst[e]], 1);
}

// ---- 3-kernel exclusive scan over cnt[N] -> rowptr[N+1], 1024 elems/block ----
__global__ void scan_k1(const int* __restrict__ cnt, int* __restrict__ bsum, int N) {
    __shared__ int lds[TPB];
    int b = blockIdx.x, t = threadIdx.x;
    int base = b * 1024 + t * 4;
    int s = 0;
    #pragma unroll
    for (int j = 0; j < 4; ++j) { int i = base + j; if (i < N) s += cnt[i]; }
    lds[t] = s; __syncthreads();
    for (int off = 128; off > 0; off >>= 1) {
        if (t < off) lds[t] += lds[t + off];
        __syncthreads();
    }
    if (t == 0) bsum[b] = lds[0];
}

__global__ void scan_k2(int* __restrict__ bsum, int NB) {
    __shared__ int lds[1024];
    int t = threadIdx.x;
    int v = (t < NB) ? bsum[t] : 0;
    lds[t] = v; __syncthreads();
    for (int off = 1; off < 1024; off <<= 1) {
        int add = (t >= off) ? lds[t - off] : 0;
        __syncthreads();
        lds[t] += add;
        __syncthreads();
    }
    if (t < NB) bsum[t] = lds[t] - v;  // exclusive
}

// local scan + add block offset; also emits dinv and z1 = x*dinv
__global__ void scan_k3(const int* __restrict__ cnt, const int* __restrict__ bsum,
                        int* __restrict__ rowptr,
                        const float* __restrict__ x, float* __restrict__ dinv,
                        float* __restrict__ z1, int N, int E) {
    __shared__ int lds[TPB];
    int b = blockIdx.x, t = threadIdx.x;
    int base = b * 1024 + t * 4;
    int v[4]; int s = 0;
    #pragma unroll
    for (int j = 0; j < 4; ++j) { int i = base + j; v[j] = (i < N) ? cnt[i] : 0; s += v[j]; }
    int orig = s;
    lds[t] = s; __syncthreads();
    for (int off = 1; off < 256; off <<= 1) {
        int add = (t >= off) ? lds[t - off] : 0;
        __syncthreads();
        lds[t] += add;
        __syncthreads();
    }
    int run = bsum[b] + lds[t] - orig;
    #pragma unroll
    for (int j = 0; j < 4; ++j) {
        int i = base + j;
        if (i < N) {
            rowptr[i] = run; run += v[j];
            float di = rsqrtf((float)v[j] + 1.0f);
            dinv[i] = di;
            float2 xv = ((const float2*)x)[i];
            ((float2*)z1)[i] = make_float2(xv.x * di, xv.y * di);
        }
    }
    if (b == 0 && t == 0) rowptr[N] = E;  // total = E always
}

__global__ void fill_pk(const int* __restrict__ dst, const unsigned* __restrict__ pk,
                        const int* __restrict__ rowptr, unsigned* __restrict__ csr, int E) {
    int e = blockIdx.x * blockDim.x + threadIdx.x;
    if (e < E) {
        unsigned p = pk[e];
        int v = dst[e];
        csr[rowptr[v] + (int)(p >> 19)] = p & 0x7FFFFu;
    }
}

__global__ void fill_cur(const int* __restrict__ dst, const int* __restrict__ src,
                         const int* __restrict__ rowptr, int* __restrict__ cur,
                         unsigned* __restrict__ csr, int E) {
    int e = blockIdx.x * blockDim.x + threadIdx.x;
    if (e < E) {
        int v = dst[e];
        int r = atomicAdd(&cur[v], 1);
        csr[rowptr[v] + r] = (unsigned)src[e];
    }
}

// layer 1: gather z1(2ch) -> z2(4ch) = tanh((dinv*(s+z1))@W1+b1)*dinv
__global__ void gcn1(const int* __restrict__ rowptr, const unsigned* __restrict__ csr,
                     const float* __restrict__ z1, const float* __restrict__ W1,
                     const float* __restrict__ b1, const float* __restrict__ dinv,
                     float* __restrict__ z2, int N) {
    int i = blockIdx.x * blockDim.x + threadIdx.x;
    if (i >= N) return;
    int r0 = rowptr[i], r1 = rowptr[i + 1];
    float2 zi = ((const float2*)z1)[i];
    float a0 = zi.x, a1 = zi.y;
    for (int k = r0; k < r1; ++k) {
        unsigned j = csr[k];
        float2 zv = ((const float2*)z1)[j];
        a0 += zv.x; a1 += zv.y;
    }
    float di = dinv[i];
    float g0 = di * a0, g1 = di * a1;
    float4 o;
    o.x = di * tanhf(fmaf(g0, W1[0], fmaf(g1, W1[4], b1[0])));
    o.y = di * tanhf(fmaf(g0, W1[1], fmaf(g1, W1[5], b1[1])));
    o.z = di * tanhf(fmaf(g0, W1[2], fmaf(g1, W1[6], b1[2])));
    o.w = di * tanhf(fmaf(g0, W1[3], fmaf(g1, W1[7], b1[3])));
    ((float4*)z2)[i] = o;
}

// layer 2 (+ early W3): gather z2(4ch) -> z3(2ch) = (tanh((dinv*(s+z2))@W2+b2)@W3)*dinv
__global__ void gcn2(const int* __restrict__ rowptr, const unsigned* __restrict__ csr,
                     const float* __restrict__ z2, const float* __restrict__ W2,
                     const float* __restrict__ b2, const float* __restrict__ W3,
                     const float* __restrict__ dinv, float* __restrict__ z3, int N) {
    int i = blockIdx.x * blockDim.x + threadIdx.x;
    if (i >= N) return;
    int r0 = rowptr[i], r1 = rowptr[i + 1];
    float4 a = ((const float4*)z2)[i];
    for (int k = r0; k < r1; ++k) {
        unsigned j = csr[k];
        float4 zv = ((const float4*)z2)[j];
        a.x += zv.x; a.y += zv.y; a.z += zv.z; a.w += zv.w;
    }
    float di = dinv[i];
    float g0 = di * a.x, g1 = di * a.y, g2 = di * a.z, g3 = di * a.w;
    float h[4];
    #pragma unroll
    for (int c = 0; c < 4; ++c)
        h[c] = tanhf(b2[c] + g0 * W2[c] + g1 * W2[4 + c] + g2 * W2[8 + c] + g3 * W2[12 + c]);
    float v0 = h[0] * W3[0] + h[1] * W3[2] + h[2] * W3[4] + h[3] * W3[6];
    float v1 = h[0] * W3[1] + h[1] * W3[3] + h[2] * W3[5] + h[3] * W3[7];
    ((float2*)z3)[i] = make_float2(v0 * di, v1 * di);
}

// layer 3: gather z3(2ch) -> out = dinv*(s+z3) + b3
__global__ void gcn3(const int* __restrict__ rowptr, const unsigned* __restrict__ csr,
                     const float* __restrict__ z3, const float* __restrict__ b3,
                     const float* __restrict__ dinv, float* __restrict__ out, int N) {
    int i = blockIdx.x * blockDim.x + threadIdx.x;
    if (i >= N) return;
    int r0 = rowptr[i], r1 = rowptr[i + 1];
    float2 zi = ((const float2*)z3)[i];
    float a0 = zi.x, a1 = zi.y;
    for (int k = r0; k < r1; ++k) {
        unsigned j = csr[k];
        float2 zv = ((const float2*)z3)[j];
        a0 += zv.x; a1 += zv.y;
    }
    float di = dinv[i];
    ((float2*)out)[i] = make_float2(fmaf(di, a0, b3[0]), fmaf(di, a1, b3[1]));
}

extern "C" void kernel_launch(void* const* d_in, const int* in_sizes, int n_in,
                              void* d_out, int out_size, void* d_ws, size_t ws_size,
                              hipStream_t stream) {
    const float* x  = (const float*)d_in[0];
    const int*   ei = (const int*)d_in[1];
    const float* W1 = (const float*)d_in[2];
    const float* b1 = (const float*)d_in[3];
    const float* W2 = (const float*)d_in[4];
    const float* b2 = (const float*)d_in[5];
    const float* W3 = (const float*)d_in[6];
    const float* b3 = (const float*)d_in[7];
    float* out = (float*)d_out;

    const int N = in_sizes[0] / 2;
    const int E = in_sizes[1] / 2;
    const int* src = ei;
    const int* dst = ei + E;

    // ws layout (256B-aligned regions)
    auto align = [](size_t o) { return (o + 255) & ~(size_t)255; };
    char* base = (char*)d_ws;
    size_t off = 0;
    int*      cnt    = (int*)(base + off);      off = align(off + (size_t)N * 4);
    int*      rowptr = (int*)(base + off);      off = align(off + (size_t)(N + 1) * 4);
    float*    dinv   = (float*)(base + off);    off = align(off + (size_t)N * 4);
    float*    z1     = (float*)(base + off);    off = align(off + (size_t)2 * N * 4);
    float*    z2     = (float*)(base + off);    off = align(off + (size_t)4 * N * 4);
    float*    z3     = (float*)(base + off);    off = align(off + (size_t)2 * N * 4);
    int*      bsum   = (int*)(base + off);      off = align(off + (size_t)1024 * 4);
    unsigned* csr    = (unsigned*)(base + off); off = align(off + (size_t)E * 4);
    size_t need_base = off;
    unsigned* pk     = (unsigned*)(base + off); off = align(off + (size_t)E * 4);
    size_t need_pk = off;
    bool use_pk = (ws_size >= need_pk);
    (void)need_base;

    const int NB = (N + 1023) / 1024;  // scan blocks (<= 1024)

    dim3 blk(TPB);
    dim3 gE((E + TPB - 1) / TPB);
    dim3 gN((N + TPB - 1) / TPB);
    dim3 gZ((N + TPB - 1) / TPB);

    zero_int<<<gZ, blk, 0, stream>>>(cnt, N);
    if (use_pk) {
        count_rank<<<gE, blk, 0, stream>>>(dst, src, cnt, pk, E);
    } else {
        count_only<<<gE, blk, 0, stream>>>(dst, cnt, E);
    }
    scan_k1<<<dim3(NB), blk, 0, stream>>>(cnt, bsum, N);
    scan_k2<<<dim3(1), dim3(1024), 0, stream>>>(bsum, NB);
    scan_k3<<<dim3(NB), blk, 0, stream>>>(cnt, bsum, rowptr, x, dinv, z1, N, E);
    if (use_pk) {
        fill_pk<<<gE, blk, 0, stream>>>(dst, pk, rowptr, csr, E);
    } else {
        zero_int<<<gZ, blk, 0, stream>>>(cnt, N);  // reuse as cursor
        fill_cur<<<gE, blk, 0, stream>>>(dst, src, rowptr, cnt, csr, E);
    }
    gcn1<<<gN, blk, 0, stream>>>(rowptr, csr, z1, W1, b1, dinv, z2, N);
    gcn2<<<gN, blk, 0, stream>>>(rowptr, csr, z2, W2, b2, W3, dinv, z3, N);
    gcn3<<<gN, blk, 0, stream>>>(rowptr, csr, z3, b3, dinv, out, N);
}

// Round 3
// 1559.502 us; speedup vs baseline: 4.5861x; 1.4371x over previous
//
#include <hip/hip_runtime.h>

// GCN 3-layer via CSR gather (no fp32 atomics).
// Per layer (input u): z = u*dinv; s_i = sum_{e:dst=i} z[src_e];
//   out_i = (dinv_i*(s_i + z_i)) @ W + b   (self-loop folds into s+z).
// Build: rank_e = atomicAdd(cnt[dst_e],1) (int, with return), pk_e = src|rank<<19;
//   rowptr = exscan(cnt); csr[rowptr[dst]+rank] = src  (no atomics in fill).
// Gather loops unrolled (U=16 / U=8) to keep many z-gathers in flight per wave
// (un-unrolled version is 1 outstanding gather/wave -> latency-bound ~270us/layer).

#define TPB 256

__global__ void zero_int(int* p, int n) {
    int i = blockIdx.x * blockDim.x + threadIdx.x;
    if (i < n) p[i] = 0;
}

// pk path: count + store packed (src | rank<<19). N < 2^19, rank < 2^13.
__global__ void count_rank(const int* __restrict__ dst, const int* __restrict__ src,
                           int* __restrict__ cnt, unsigned* __restrict__ pk, int E) {
    int e = blockIdx.x * blockDim.x + threadIdx.x;
    if (e < E) {
        int v = dst[e];
        int r = atomicAdd(&cnt[v], 1);
        pk[e] = (unsigned)src[e] | ((unsigned)r << 19);
    }
}

// cursor path: count only
__global__ void count_only(const int* __restrict__ dst, int* __restrict__ cnt, int E) {
    int e = blockIdx.x * blockDim.x + threadIdx.x;
    if (e < E) atomicAdd(&cnt[dst[e]], 1);
}

// ---- 3-kernel exclusive scan over cnt[N] -> rowptr[N+1], 1024 elems/block ----
__global__ void scan_k1(const int* __restrict__ cnt, int* __restrict__ bsum, int N) {
    __shared__ int lds[TPB];
    int b = blockIdx.x, t = threadIdx.x;
    int base = b * 1024 + t * 4;
    int s = 0;
    #pragma unroll
    for (int j = 0; j < 4; ++j) { int i = base + j; if (i < N) s += cnt[i]; }
    lds[t] = s; __syncthreads();
    for (int off = 128; off > 0; off >>= 1) {
        if (t < off) lds[t] += lds[t + off];
        __syncthreads();
    }
    if (t == 0) bsum[b] = lds[0];
}

__global__ void scan_k2(int* __restrict__ bsum, int NB) {
    __shared__ int lds[1024];
    int t = threadIdx.x;
    int v = (t < NB) ? bsum[t] : 0;
    lds[t] = v; __syncthreads();
    for (int off = 1; off < 1024; off <<= 1) {
        int add = (t >= off) ? lds[t - off] : 0;
        __syncthreads();
        lds[t] += add;
        __syncthreads();
    }
    if (t < NB) bsum[t] = lds[t] - v;  // exclusive
}

// local scan + add block offset; also emits dinv and z1 = x*dinv
__global__ void scan_k3(const int* __restrict__ cnt, const int* __restrict__ bsum,
                        int* __restrict__ rowptr,
                        const float* __restrict__ x, float* __restrict__ dinv,
                        float* __restrict__ z1, int N, int E) {
    __shared__ int lds[TPB];
    int b = blockIdx.x, t = threadIdx.x;
    int base = b * 1024 + t * 4;
    int v[4]; int s = 0;
    #pragma unroll
    for (int j = 0; j < 4; ++j) { int i = base + j; v[j] = (i < N) ? cnt[i] : 0; s += v[j]; }
    int orig = s;
    lds[t] = s; __syncthreads();
    for (int off = 1; off < 256; off <<= 1) {
        int add = (t >= off) ? lds[t - off] : 0;
        __syncthreads();
        lds[t] += add;
        __syncthreads();
    }
    int run = bsum[b] + lds[t] - orig;
    #pragma unroll
    for (int j = 0; j < 4; ++j) {
        int i = base + j;
        if (i < N) {
            rowptr[i] = run; run += v[j];
            float di = rsqrtf((float)v[j] + 1.0f);
            dinv[i] = di;
            float2 xv = ((const float2*)x)[i];
            ((float2*)z1)[i] = make_float2(xv.x * di, xv.y * di);
        }
    }
    if (b == 0 && t == 0) rowptr[N] = E;  // total = E always
}

__global__ void fill_pk(const int* __restrict__ dst, const unsigned* __restrict__ pk,
                        const int* __restrict__ rowptr, unsigned* __restrict__ csr, int E) {
    int e = blockIdx.x * blockDim.x + threadIdx.x;
    if (e < E) {
        unsigned p = pk[e];
        int v = dst[e];
        csr[rowptr[v] + (int)(p >> 19)] = p & 0x7FFFFu;
    }
}

__global__ void fill_cur(const int* __restrict__ dst, const int* __restrict__ src,
                         const int* __restrict__ rowptr, int* __restrict__ cur,
                         unsigned* __restrict__ csr, int E) {
    int e = blockIdx.x * blockDim.x + threadIdx.x;
    if (e < E) {
        int v = dst[e];
        int r = atomicAdd(&cur[v], 1);
        csr[rowptr[v] + r] = (unsigned)src[e];
    }
}

// layer 1: gather z1(2ch) -> z2(4ch) = tanh((dinv*(s+z1))@W1+b1)*dinv
__global__ void gcn1(const int* __restrict__ rowptr, const unsigned* __restrict__ csr,
                     const float* __restrict__ z1, const float* __restrict__ W1,
                     const float* __restrict__ b1, const float* __restrict__ dinv,
                     float* __restrict__ z2, int N) {
    int i = blockIdx.x * blockDim.x + threadIdx.x;
    if (i >= N) return;
    int r0 = rowptr[i], r1 = rowptr[i + 1];
    float2 zi = ((const float2*)z1)[i];
    float a0 = zi.x, a1 = zi.y;
    const float2* z = (const float2*)z1;
    int k = r0;
    for (; k + 16 <= r1; k += 16) {
        unsigned j[16];
        #pragma unroll
        for (int u = 0; u < 16; ++u) j[u] = csr[k + u];
        float2 v[16];
        #pragma unroll
        for (int u = 0; u < 16; ++u) v[u] = z[j[u]];
        #pragma unroll
        for (int u = 0; u < 16; ++u) { a0 += v[u].x; a1 += v[u].y; }
    }
    for (; k < r1; ++k) {
        float2 zv = z[csr[k]];
        a0 += zv.x; a1 += zv.y;
    }
    float di = dinv[i];
    float g0 = di * a0, g1 = di * a1;
    float4 o;
    o.x = di * tanhf(fmaf(g0, W1[0], fmaf(g1, W1[4], b1[0])));
    o.y = di * tanhf(fmaf(g0, W1[1], fmaf(g1, W1[5], b1[1])));
    o.z = di * tanhf(fmaf(g0, W1[2], fmaf(g1, W1[6], b1[2])));
    o.w = di * tanhf(fmaf(g0, W1[3], fmaf(g1, W1[7], b1[3])));
    ((float4*)z2)[i] = o;
}

// layer 2 (+ early W3): gather z2(4ch) -> z3(2ch) = (tanh((dinv*(s+z2))@W2+b2)@W3)*dinv
__global__ void gcn2(const int* __restrict__ rowptr, const unsigned* __restrict__ csr,
                     const float* __restrict__ z2, const float* __restrict__ W2,
                     const float* __restrict__ b2, const float* __restrict__ W3,
                     const float* __restrict__ dinv, float* __restrict__ z3, int N) {
    int i = blockIdx.x * blockDim.x + threadIdx.x;
    if (i >= N) return;
    int r0 = rowptr[i], r1 = rowptr[i + 1];
    float4 a = ((const float4*)z2)[i];
    const float4* z = (const float4*)z2;
    int k = r0;
    for (; k + 8 <= r1; k += 8) {
        unsigned j[8];
        #pragma unroll
        for (int u = 0; u < 8; ++u) j[u] = csr[k + u];
        float4 v[8];
        #pragma unroll
        for (int u = 0; u < 8; ++u) v[u] = z[j[u]];
        #pragma unroll
        for (int u = 0; u < 8; ++u) {
            a.x += v[u].x; a.y += v[u].y; a.z += v[u].z; a.w += v[u].w;
        }
    }
    for (; k < r1; ++k) {
        float4 zv = z[csr[k]];
        a.x += zv.x; a.y += zv.y; a.z += zv.z; a.w += zv.w;
    }
    float di = dinv[i];
    float g0 = di * a.x, g1 = di * a.y, g2 = di * a.z, g3 = di * a.w;
    float h[4];
    #pragma unroll
    for (int c = 0; c < 4; ++c)
        h[c] = tanhf(b2[c] + g0 * W2[c] + g1 * W2[4 + c] + g2 * W2[8 + c] + g3 * W2[12 + c]);
    float v0 = h[0] * W3[0] + h[1] * W3[2] + h[2] * W3[4] + h[3] * W3[6];
    float v1 = h[0] * W3[1] + h[1] * W3[3] + h[2] * W3[5] + h[3] * W3[7];
    ((float2*)z3)[i] = make_float2(v0 * di, v1 * di);
}

// layer 3: gather z3(2ch) -> out = dinv*(s+z3) + b3
__global__ void gcn3(const int* __restrict__ rowptr, const unsigned* __restrict__ csr,
                     const float* __restrict__ z3, const float* __restrict__ b3,
                     const float* __restrict__ dinv, float* __restrict__ out, int N) {
    int i = blockIdx.x * blockDim.x + threadIdx.x;
    if (i >= N) return;
    int r0 = rowptr[i], r1 = rowptr[i + 1];
    float2 zi = ((const float2*)z3)[i];
    float a0 = zi.x, a1 = zi.y;
    const float2* z = (const float2*)z3;
    int k = r0;
    for (; k + 16 <= r1; k += 16) {
        unsigned j[16];
        #pragma unroll
        for (int u = 0; u < 16; ++u) j[u] = csr[k + u];
        float2 v[16];
        #pragma unroll
        for (int u = 0; u < 16; ++u) v[u] = z[j[u]];
        #pragma unroll
        for (int u = 0; u < 16; ++u) { a0 += v[u].x; a1 += v[u].y; }
    }
    for (; k < r1; ++k) {
        float2 zv = z[csr[k]];
        a0 += zv.x; a1 += zv.y;
    }
    float di = dinv[i];
    ((float2*)out)[i] = make_float2(fmaf(di, a0, b3[0]), fmaf(di, a1, b3[1]));
}

extern "C" void kernel_launch(void* const* d_in, const int* in_sizes, int n_in,
                              void* d_out, int out_size, void* d_ws, size_t ws_size,
                              hipStream_t stream) {
    const float* x  = (const float*)d_in[0];
    const int*   ei = (const int*)d_in[1];
    const float* W1 = (const float*)d_in[2];
    const float* b1 = (const float*)d_in[3];
    const float* W2 = (const float*)d_in[4];
    const float* b2 = (const float*)d_in[5];
    const float* W3 = (const float*)d_in[6];
    const float* b3 = (const float*)d_in[7];
    float* out = (float*)d_out;

    const int N = in_sizes[0] / 2;
    const int E = in_sizes[1] / 2;
    const int* src = ei;
    const int* dst = ei + E;

    // ws layout (256B-aligned regions)
    auto align = [](size_t o) { return (o + 255) & ~(size_t)255; };
    char* base = (char*)d_ws;
    size_t off = 0;
    int*      cnt    = (int*)(base + off);      off = align(off + (size_t)N * 4);
    int*      rowptr = (int*)(base + off);      off = align(off + (size_t)(N + 1) * 4);
    float*    dinv   = (float*)(base + off);    off = align(off + (size_t)N * 4);
    float*    z1     = (float*)(base + off);    off = align(off + (size_t)2 * N * 4);
    float*    z2     = (float*)(base + off);    off = align(off + (size_t)4 * N * 4);
    float*    z3     = (float*)(base + off);    off = align(off + (size_t)2 * N * 4);
    int*      bsum   = (int*)(base + off);      off = align(off + (size_t)1024 * 4);
    unsigned* csr    = (unsigned*)(base + off); off = align(off + (size_t)E * 4);
    size_t need_base = off;
    unsigned* pk     = (unsigned*)(base + off); off = align(off + (size_t)E * 4);
    size_t need_pk = off;
    bool use_pk = (ws_size >= need_pk);
    (void)need_base;

    const int NB = (N + 1023) / 1024;  // scan blocks (<= 1024)

    dim3 blk(TPB);
    dim3 gE((E + TPB - 1) / TPB);
    dim3 gN((N + TPB - 1) / TPB);
    dim3 gZ((N + TPB - 1) / TPB);

    zero_int<<<gZ, blk, 0, stream>>>(cnt, N);
    if (use_pk) {
        count_rank<<<gE, blk, 0, stream>>>(dst, src, cnt, pk, E);
    } else {
        count_only<<<gE, blk, 0, stream>>>(dst, cnt, E);
    }
    scan_k1<<<dim3(NB), blk, 0, stream>>>(cnt, bsum, N);
    scan_k2<<<dim3(1), dim3(1024), 0, stream>>>(bsum, NB);
    scan_k3<<<dim3(NB), blk, 0, stream>>>(cnt, bsum, rowptr, x, dinv, z1, N, E);
    if (use_pk) {
        fill_pk<<<gE, blk, 0, stream>>>(dst, pk, rowptr, csr, E);
    } else {
        zero_int<<<gZ, blk, 0, stream>>>(cnt, N);  // reuse as cursor
        fill_cur<<<gE, blk, 0, stream>>>(dst, src, rowptr, cnt, csr, E);
    }
    gcn1<<<gN, blk, 0, stream>>>(rowptr, csr, z1, W1, b1, dinv, z2, N);
    gcn2<<<gN, blk, 0, stream>>>(rowptr, csr, z2, W2, b2, W3, dinv, z3, N);
    gcn3<<<gN, blk, 0, stream>>>(rowptr, csr, z3, b3, dinv, out, N);
}

// Round 4
// 1234.593 us; speedup vs baseline: 5.7930x; 1.2632x over previous
//
#include <hip/hip_runtime.h>

// GCN 3-layer via bucketed CSR build (zero global atomics) + unrolled gather.
// Math per layer (input u): z = u*dinv; s_i = sum_{e:dst=i} z[src_e];
//   out_i = (dinv_i*(s_i + z_i)) @ W + b   (self-loop folds into s+z).
// Build: buckets of 512 nodes (B=977). tilecount -> cntmat[b][t] LDS histograms;
// exclusive scan of cntmat gives deterministic scatter bases (no atomics);
// bucketscatter packs (dst&511)|(src<<9) into contiguous bucket regions
// (L2-resident, write-back); bucketbuild does per-bucket LDS count/scan ->
// rowptr+dinv+z1 and LDS-cursor CSR placement. Assumes N < 2^19, NPB=512.

#define TPB 256
#define T_TILE 16384

// ---------------- CSR build ----------------

__global__ void tilecount(const int* __restrict__ dst, int* __restrict__ cntmat,
                          int ntiles, int E, int B) {
    __shared__ int hist[1024];
    int blk = blockIdx.x, tid = threadIdx.x;
    hist[tid] = 0; hist[tid + 256] = 0; hist[tid + 512] = 0; hist[tid + 768] = 0;
    __syncthreads();
    int base = blk * T_TILE;
    #pragma unroll 4
    for (int it = 0; it < T_TILE / 256; ++it) {
        int e = base + it * 256 + tid;
        if (e < E) atomicAdd(&hist[((unsigned)dst[e]) >> 9], 1);
    }
    __syncthreads();
    for (int l = tid; l < B; l += 256)
        cntmat[(size_t)l * ntiles + blk] = hist[l];
}

// ---- 3-kernel exclusive scan over data[len] (in-place), 1024 elems/block ----
__global__ void scan_k1(const int* __restrict__ data, int* __restrict__ bsum, int len) {
    __shared__ int lds[TPB];
    int b = blockIdx.x, t = threadIdx.x;
    int base = b * 1024 + t * 4;
    int s = 0;
    #pragma unroll
    for (int j = 0; j < 4; ++j) { int i = base + j; if (i < len) s += data[i]; }
    lds[t] = s; __syncthreads();
    for (int off = 128; off > 0; off >>= 1) {
        if (t < off) lds[t] += lds[t + off];
        __syncthreads();
    }
    if (t == 0) bsum[b] = lds[0];
}

__global__ void scan_k2(int* __restrict__ bsum, int NB) {
    __shared__ int lds[1024];
    int t = threadIdx.x;
    int v = (t < NB) ? bsum[t] : 0;
    lds[t] = v; __syncthreads();
    for (int off = 1; off < 1024; off <<= 1) {
        int add = (t >= off) ? lds[t - off] : 0;
        __syncthreads();
        lds[t] += add;
        __syncthreads();
    }
    if (t < NB) bsum[t] = lds[t] - v;  // exclusive
}

__global__ void scan_k3(int* __restrict__ data, const int* __restrict__ bsum, int len) {
    __shared__ int lds[TPB];
    int b = blockIdx.x, t = threadIdx.x;
    int base = b * 1024 + t * 4;
    int v[4]; int s = 0;
    #pragma unroll
    for (int j = 0; j < 4; ++j) { int i = base + j; v[j] = (i < len) ? data[i] : 0; s += v[j]; }
    int orig = s;
    lds[t] = s; __syncthreads();
    for (int off = 1; off < 256; off <<= 1) {
        int add = (t >= off) ? lds[t - off] : 0;
        __syncthreads();
        lds[t] += add;
        __syncthreads();
    }
    int run = bsum[b] + lds[t] - orig;
    #pragma unroll
    for (int j = 0; j < 4; ++j) {
        int i = base + j;
        if (i < len) { data[i] = run; run += v[j]; }
    }
}

__global__ void bucketscatter(const int* __restrict__ dst, const int* __restrict__ src,
                              const int* __restrict__ scanM, unsigned* __restrict__ pk32,
                              int ntiles, int E, int B) {
    __shared__ int basec[1024];
    int blk = blockIdx.x, tid = threadIdx.x;
    for (int l = tid; l < B; l += 256)
        basec[l] = scanM[(size_t)l * ntiles + blk];
    __syncthreads();
    int base = blk * T_TILE;
    #pragma unroll 4
    for (int it = 0; it < T_TILE / 256; ++it) {
        int e = base + it * 256 + tid;
        if (e < E) {
            int d = dst[e];
            int s = src[e];
            int pos = atomicAdd(&basec[((unsigned)d) >> 9], 1);
            pk32[pos] = ((unsigned)d & 511u) | ((unsigned)s << 9);
        }
    }
}

// Per bucket: LDS count (512), LDS scan -> rowptr/dinv/z1, then CSR placement.
__global__ void bucketbuild(const int* __restrict__ scanM, const unsigned* __restrict__ pk32,
                            int ntiles, const float* __restrict__ x,
                            int* __restrict__ rowptr, float* __restrict__ dinv,
                            float* __restrict__ z1, unsigned* __restrict__ csr,
                            int N, int E, int B) {
    __shared__ int cnt[512];
    __shared__ int tmp[TPB];
    __shared__ int sbase, sn;
    int b = blockIdx.x, tid = threadIdx.x;
    if (tid == 0) {
        int s0 = scanM[(size_t)b * ntiles];
        int s1 = (b + 1 < B) ? scanM[(size_t)(b + 1) * ntiles] : E;
        sbase = s0; sn = s1 - s0;
    }
    cnt[tid] = 0; cnt[tid + 256] = 0;
    __syncthreads();
    int base = sbase, n = sn;
    for (int k = tid; k < n; k += 256)
        atomicAdd(&cnt[pk32[base + k] & 511u], 1);
    __syncthreads();
    int c0 = cnt[2 * tid], c1 = cnt[2 * tid + 1];
    int s = c0 + c1;
    tmp[tid] = s; __syncthreads();
    for (int off = 1; off < 256; off <<= 1) {
        int add = (tid >= off) ? tmp[tid - off] : 0;
        __syncthreads();
        tmp[tid] += add;
        __syncthreads();
    }
    int excl = tmp[tid] - s;  // exclusive prefix of pair-sums
    int i0 = b << 9;
    int i = i0 + 2 * tid;
    if (i < N) {
        rowptr[i] = base + excl;
        float di = rsqrtf((float)c0 + 1.0f);
        dinv[i] = di;
        float2 xv = ((const float2*)x)[i];
        ((float2*)z1)[i] = make_float2(xv.x * di, xv.y * di);
    }
    if (i + 1 < N) {
        rowptr[i + 1] = base + excl + c0;
        float di = rsqrtf((float)c1 + 1.0f);
        dinv[i + 1] = di;
        float2 xv = ((const float2*)x)[i + 1];
        ((float2*)z1)[i + 1] = make_float2(xv.x * di, xv.y * di);
    }
    if (b == B - 1 && tid == 0) rowptr[N] = E;
    __syncthreads();
    cnt[2 * tid] = excl;            // reuse as local cursors
    cnt[2 * tid + 1] = excl + c0;
    __syncthreads();
    for (int k = tid; k < n; k += 256) {
        unsigned p = pk32[base + k];
        int pos = base + atomicAdd(&cnt[p & 511u], 1);
        csr[pos] = p >> 9;          // src node id
    }
}

// ---------------- GCN layers (unrolled gathers) ----------------

__global__ void gcn1(const int* __restrict__ rowptr, const unsigned* __restrict__ csr,
                     const float* __restrict__ z1, const float* __restrict__ W1,
                     const float* __restrict__ b1, const float* __restrict__ dinv,
                     float* __restrict__ z2, int N) {
    int i = blockIdx.x * blockDim.x + threadIdx.x;
    if (i >= N) return;
    int r0 = rowptr[i], r1 = rowptr[i + 1];
    float2 zi = ((const float2*)z1)[i];
    float a0 = zi.x, a1 = zi.y;
    const float2* z = (const float2*)z1;
    int k = r0;
    for (; k + 16 <= r1; k += 16) {
        unsigned j[16];
        #pragma unroll
        for (int u = 0; u < 16; ++u) j[u] = csr[k + u];
        float2 v[16];
        #pragma unroll
        for (int u = 0; u < 16; ++u) v[u] = z[j[u]];
        #pragma unroll
        for (int u = 0; u < 16; ++u) { a0 += v[u].x; a1 += v[u].y; }
    }
    for (; k < r1; ++k) {
        float2 zv = z[csr[k]];
        a0 += zv.x; a1 += zv.y;
    }
    float di = dinv[i];
    float g0 = di * a0, g1 = di * a1;
    float4 o;
    o.x = di * tanhf(fmaf(g0, W1[0], fmaf(g1, W1[4], b1[0])));
    o.y = di * tanhf(fmaf(g0, W1[1], fmaf(g1, W1[5], b1[1])));
    o.z = di * tanhf(fmaf(g0, W1[2], fmaf(g1, W1[6], b1[2])));
    o.w = di * tanhf(fmaf(g0, W1[3], fmaf(g1, W1[7], b1[3])));
    ((float4*)z2)[i] = o;
}

__global__ void gcn2(const int* __restrict__ rowptr, const unsigned* __restrict__ csr,
                     const float* __restrict__ z2, const float* __restrict__ W2,
                     const float* __restrict__ b2, const float* __restrict__ W3,
                     const float* __restrict__ dinv, float* __restrict__ z3, int N) {
    int i = blockIdx.x * blockDim.x + threadIdx.x;
    if (i >= N) return;
    int r0 = rowptr[i], r1 = rowptr[i + 1];
    float4 a = ((const float4*)z2)[i];
    const float4* z = (const float4*)z2;
    int k = r0;
    for (; k + 8 <= r1; k += 8) {
        unsigned j[8];
        #pragma unroll
        for (int u = 0; u < 8; ++u) j[u] = csr[k + u];
        float4 v[8];
        #pragma unroll
        for (int u = 0; u < 8; ++u) v[u] = z[j[u]];
        #pragma unroll
        for (int u = 0; u < 8; ++u) {
            a.x += v[u].x; a.y += v[u].y; a.z += v[u].z; a.w += v[u].w;
        }
    }
    for (; k < r1; ++k) {
        float4 zv = z[csr[k]];
        a.x += zv.x; a.y += zv.y; a.z += zv.z; a.w += zv.w;
    }
    float di = dinv[i];
    float g0 = di * a.x, g1 = di * a.y, g2 = di * a.z, g3 = di * a.w;
    float h[4];
    #pragma unroll
    for (int c = 0; c < 4; ++c)
        h[c] = tanhf(b2[c] + g0 * W2[c] + g1 * W2[4 + c] + g2 * W2[8 + c] + g3 * W2[12 + c]);
    float v0 = h[0] * W3[0] + h[1] * W3[2] + h[2] * W3[4] + h[3] * W3[6];
    float v1 = h[0] * W3[1] + h[1] * W3[3] + h[2] * W3[5] + h[3] * W3[7];
    ((float2*)z3)[i] = make_float2(v0 * di, v1 * di);
}

__global__ void gcn3(const int* __restrict__ rowptr, const unsigned* __restrict__ csr,
                     const float* __restrict__ z3, const float* __restrict__ b3,
                     const float* __restrict__ dinv, float* __restrict__ out, int N) {
    int i = blockIdx.x * blockDim.x + threadIdx.x;
    if (i >= N) return;
    int r0 = rowptr[i], r1 = rowptr[i + 1];
    float2 zi = ((const float2*)z3)[i];
    float a0 = zi.x, a1 = zi.y;
    const float2* z = (const float2*)z3;
    int k = r0;
    for (; k + 16 <= r1; k += 16) {
        unsigned j[16];
        #pragma unroll
        for (int u = 0; u < 16; ++u) j[u] = csr[k + u];
        float2 v[16];
        #pragma unroll
        for (int u = 0; u < 16; ++u) v[u] = z[j[u]];
        #pragma unroll
        for (int u = 0; u < 16; ++u) { a0 += v[u].x; a1 += v[u].y; }
    }
    for (; k < r1; ++k) {
        float2 zv = z[csr[k]];
        a0 += zv.x; a1 += zv.y;
    }
    float di = dinv[i];
    ((float2*)out)[i] = make_float2(fmaf(di, a0, b3[0]), fmaf(di, a1, b3[1]));
}

extern "C" void kernel_launch(void* const* d_in, const int* in_sizes, int n_in,
                              void* d_out, int out_size, void* d_ws, size_t ws_size,
                              hipStream_t stream) {
    const float* x  = (const float*)d_in[0];
    const int*   ei = (const int*)d_in[1];
    const float* W1 = (const float*)d_in[2];
    const float* b1 = (const float*)d_in[3];
    const float* W2 = (const float*)d_in[4];
    const float* b2 = (const float*)d_in[5];
    const float* W3 = (const float*)d_in[6];
    const float* b3 = (const float*)d_in[7];
    float* out = (float*)d_out;

    const int N = in_sizes[0] / 2;
    const int E = in_sizes[1] / 2;
    const int* src = ei;
    const int* dst = ei + E;

    const int B = (N + 511) >> 9;                     // buckets of 512 nodes (977)
    const int ntiles = (E + T_TILE - 1) / T_TILE;     // 977
    const int mlen = B * ntiles;                      // cntmat length (~954K)
    const int NB = (mlen + 1023) / 1024;              // scan blocks (<=1024)

    // ws layout (256B-aligned). cntmat overlays z2 (z2 written only later by gcn1).
    auto align = [](size_t o) { return (o + 255) & ~(size_t)255; };
    char* base = (char*)d_ws;
    size_t off = 0;
    int*      rowptr = (int*)(base + off);      off = align(off + (size_t)(N + 1) * 4);
    float*    dinv   = (float*)(base + off);    off = align(off + (size_t)N * 4);
    float*    z1     = (float*)(base + off);    off = align(off + (size_t)2 * N * 4);
    float*    z2     = (float*)(base + off);    off = align(off + (size_t)4 * N * 4);
    float*    z3     = (float*)(base + off);    off = align(off + (size_t)2 * N * 4);
    int*      bsum   = (int*)(base + off);      off = align(off + (size_t)1024 * 4);
    unsigned* csr    = (unsigned*)(base + off); off = align(off + (size_t)E * 4);
    unsigned* pk32   = (unsigned*)(base + off); off = align(off + (size_t)E * 4);
    int*      cntmat = (int*)z2;                // overlay: 4N*4B = 8MB >= mlen*4B

    dim3 blk(TPB);
    dim3 gN((N + TPB - 1) / TPB);

    tilecount<<<dim3(ntiles), blk, 0, stream>>>(dst, cntmat, ntiles, E, B);
    scan_k1<<<dim3(NB), blk, 0, stream>>>(cntmat, bsum, mlen);
    scan_k2<<<dim3(1), dim3(1024), 0, stream>>>(bsum, NB);
    scan_k3<<<dim3(NB), blk, 0, stream>>>(cntmat, bsum, mlen);
    bucketscatter<<<dim3(ntiles), blk, 0, stream>>>(dst, src, cntmat, pk32, ntiles, E, B);
    bucketbuild<<<dim3(B), blk, 0, stream>>>(cntmat, pk32, ntiles, x, rowptr, dinv, z1,
                                             csr, N, E, B);
    gcn1<<<gN, blk, 0, stream>>>(rowptr, csr, z1, W1, b1, dinv, z2, N);
    gcn2<<<gN, blk, 0, stream>>>(rowptr, csr, z2, W2, b2, W3, dinv, z3, N);
    gcn3<<<gN, blk, 0, stream>>>(rowptr, csr, z3, b3, dinv, out, N);
}

// Round 5
// 1048.607 us; speedup vs baseline: 6.8204x; 1.1774x over previous
//
#include <hip/hip_runtime.h>

// GCN 3-layer via bucketed CSR build (zero global atomics) + unrolled gather.
// Math per layer (input u): z = u*dinv; s_i = sum_{e:dst=i} z[src_e];
//   out_i = (dinv_i*(s_i + z_i)) @ W + b   (self-loop folds into s+z).
// Build: buckets of 4096 nodes (B=123). tilecount(T=8192) -> cntmat[b][t];
// exscan gives deterministic scatter bases; bucketscatter runs 512 persistent
// blocks x 4 consecutive tiles (write working-set 2MB/XCD < L2 -> full-line
// write-back; round-4 NPB=512/free-grid version hit 437MB WRITE for 64MB
// payload from partial-line thrash). bucketbuild: 1024thr/block, LDS cnt[4096]
// scan -> rowptr/dinv/z1 + L2-window CSR placement. N < 2^19.

#define TPB 256
#define T_TILE 8192
#define NPB 4096          // nodes per bucket (2^12)

// ---------------- CSR build ----------------

__global__ void tilecount(const int* __restrict__ dst, int* __restrict__ cntmat,
                          int ntiles, int E, int B) {
    __shared__ int hist[128];
    int blk = blockIdx.x, tid = threadIdx.x;
    if (tid < 128) hist[tid] = 0;
    __syncthreads();
    int base = blk * T_TILE;
    #pragma unroll 4
    for (int it = 0; it < T_TILE / 256; ++it) {
        int e = base + it * 256 + tid;
        if (e < E) atomicAdd(&hist[((unsigned)dst[e]) >> 12], 1);
    }
    __syncthreads();
    if (tid < B) cntmat[(size_t)tid * ntiles + blk] = hist[tid];
}

// ---- 3-kernel exclusive scan over data[len] (in-place), 1024 elems/block ----
__global__ void scan_k1(const int* __restrict__ data, int* __restrict__ bsum, int len) {
    __shared__ int lds[TPB];
    int b = blockIdx.x, t = threadIdx.x;
    int base = b * 1024 + t * 4;
    int s = 0;
    #pragma unroll
    for (int j = 0; j < 4; ++j) { int i = base + j; if (i < len) s += data[i]; }
    lds[t] = s; __syncthreads();
    for (int off = 128; off > 0; off >>= 1) {
        if (t < off) lds[t] += lds[t + off];
        __syncthreads();
    }
    if (t == 0) bsum[b] = lds[0];
}

__global__ void scan_k2(int* __restrict__ bsum, int NB) {
    __shared__ int lds[1024];
    int t = threadIdx.x;
    int v = (t < NB) ? bsum[t] : 0;
    lds[t] = v; __syncthreads();
    for (int off = 1; off < 1024; off <<= 1) {
        int add = (t >= off) ? lds[t - off] : 0;
        __syncthreads();
        lds[t] += add;
        __syncthreads();
    }
    if (t < NB) bsum[t] = lds[t] - v;  // exclusive
}

__global__ void scan_k3(int* __restrict__ data, const int* __restrict__ bsum, int len) {
    __shared__ int lds[TPB];
    int b = blockIdx.x, t = threadIdx.x;
    int base = b * 1024 + t * 4;
    int v[4]; int s = 0;
    #pragma unroll
    for (int j = 0; j < 4; ++j) { int i = base + j; v[j] = (i < len) ? data[i] : 0; s += v[j]; }
    int orig = s;
    lds[t] = s; __syncthreads();
    for (int off = 1; off < 256; off <<= 1) {
        int add = (t >= off) ? lds[t - off] : 0;
        __syncthreads();
        lds[t] += add;
        __syncthreads();
    }
    int run = bsum[b] + lds[t] - orig;
    #pragma unroll
    for (int j = 0; j < 4; ++j) {
        int i = base + j;
        if (i < len) { data[i] = run; run += v[j]; }
    }
}

// 512 blocks, each owns tilesPerBlk CONSECUTIVE tiles (bounded write set).
__global__ void bucketscatter(const int* __restrict__ dst, const int* __restrict__ src,
                              const int* __restrict__ scanM, unsigned* __restrict__ pk32,
                              int ntiles, int E, int B, int tilesPerBlk) {
    __shared__ int basec[128];
    int tid = threadIdx.x;
    int t0 = blockIdx.x * tilesPerBlk;
    for (int tt = 0; tt < tilesPerBlk; ++tt) {
        int tile = t0 + tt;
        if (tile >= ntiles) return;
        if (tid < B) basec[tid] = scanM[(size_t)tid * ntiles + tile];
        __syncthreads();
        int base = tile * T_TILE;
        #pragma unroll 4
        for (int it = 0; it < T_TILE / 256; ++it) {
            int e = base + it * 256 + tid;
            if (e < E) {
                int d = dst[e];
                int s = src[e];
                int pos = atomicAdd(&basec[((unsigned)d) >> 12], 1);
                pk32[pos] = ((unsigned)d & 4095u) | ((unsigned)s << 12);
            }
        }
        __syncthreads();  // cursors done before next tile reload
    }
}

// Per bucket (4096 nodes, 1024 threads): LDS count, block scan -> rowptr/dinv/z1,
// LDS-cursor CSR placement within the 512KB L2-resident bucket window.
__global__ void __launch_bounds__(1024)
bucketbuild(const int* __restrict__ scanM, const unsigned* __restrict__ pk32,
            int ntiles, const float* __restrict__ x,
            int* __restrict__ rowptr, float* __restrict__ dinv,
            float* __restrict__ z1, unsigned* __restrict__ csr,
            int N, int E, int B) {
    __shared__ int cnt[NPB];
    __shared__ int tmp[1024];
    __shared__ int sbase, sn;
    int b = blockIdx.x, tid = threadIdx.x;
    if (tid == 0) {
        int s0 = scanM[(size_t)b * ntiles];
        int s1 = (b + 1 < B) ? scanM[(size_t)(b + 1) * ntiles] : E;
        sbase = s0; sn = s1 - s0;
    }
    #pragma unroll
    for (int j = 0; j < 4; ++j) cnt[tid + j * 1024] = 0;
    __syncthreads();
    int base = sbase, n = sn;
    for (int k = tid; k < n; k += 1024)
        atomicAdd(&cnt[pk32[base + k] & 4095u], 1);
    __syncthreads();
    int c[4]; int s = 0;
    #pragma unroll
    for (int j = 0; j < 4; ++j) { c[j] = cnt[4 * tid + j]; s += c[j]; }
    tmp[tid] = s; __syncthreads();
    for (int off = 1; off < 1024; off <<= 1) {
        int add = (tid >= off) ? tmp[tid - off] : 0;
        __syncthreads();
        tmp[tid] += add;
        __syncthreads();
    }
    int run = tmp[tid] - s;  // exclusive prefix (relative to bucket base)
    int i0 = (b << 12) + 4 * tid;
    #pragma unroll
    for (int j = 0; j < 4; ++j) {
        int i = i0 + j;
        if (i < N) {
            rowptr[i] = base + run;
            float di = rsqrtf((float)c[j] + 1.0f);
            dinv[i] = di;
            float2 xv = ((const float2*)x)[i];
            ((float2*)z1)[i] = make_float2(xv.x * di, xv.y * di);
        }
        tmp[0] = 0;  // dummy to keep compiler from sinking; overwritten below
        cnt[4 * tid + j] = run;  // cursor (relative)
        run += c[j];
    }
    if (b == B - 1 && tid == 0) rowptr[N] = E;
    __syncthreads();
    for (int k = tid; k < n; k += 1024) {
        unsigned p = pk32[base + k];
        int pos = base + atomicAdd(&cnt[p & 4095u], 1);
        csr[pos] = p >> 12;  // src node id
    }
}

// ---------------- GCN layers (unrolled gathers) ----------------

__global__ void gcn1(const int* __restrict__ rowptr, const unsigned* __restrict__ csr,
                     const float* __restrict__ z1, const float* __restrict__ W1,
                     const float* __restrict__ b1, const float* __restrict__ dinv,
                     float* __restrict__ z2, int N) {
    int i = blockIdx.x * blockDim.x + threadIdx.x;
    if (i >= N) return;
    int r0 = rowptr[i], r1 = rowptr[i + 1];
    float2 zi = ((const float2*)z1)[i];
    float a0 = zi.x, a1 = zi.y;
    const float2* z = (const float2*)z1;
    int k = r0;
    for (; k + 16 <= r1; k += 16) {
        unsigned j[16];
        #pragma unroll
        for (int u = 0; u < 16; ++u) j[u] = csr[k + u];
        float2 v[16];
        #pragma unroll
        for (int u = 0; u < 16; ++u) v[u] = z[j[u]];
        #pragma unroll
        for (int u = 0; u < 16; ++u) { a0 += v[u].x; a1 += v[u].y; }
    }
    for (; k < r1; ++k) {
        float2 zv = z[csr[k]];
        a0 += zv.x; a1 += zv.y;
    }
    float di = dinv[i];
    float g0 = di * a0, g1 = di * a1;
    float4 o;
    o.x = di * tanhf(fmaf(g0, W1[0], fmaf(g1, W1[4], b1[0])));
    o.y = di * tanhf(fmaf(g0, W1[1], fmaf(g1, W1[5], b1[1])));
    o.z = di * tanhf(fmaf(g0, W1[2], fmaf(g1, W1[6], b1[2])));
    o.w = di * tanhf(fmaf(g0, W1[3], fmaf(g1, W1[7], b1[3])));
    ((float4*)z2)[i] = o;
}

__global__ void gcn2(const int* __restrict__ rowptr, const unsigned* __restrict__ csr,
                     const float* __restrict__ z2, const float* __restrict__ W2,
                     const float* __restrict__ b2, const float* __restrict__ W3,
                     const float* __restrict__ dinv, float* __restrict__ z3, int N) {
    int i = blockIdx.x * blockDim.x + threadIdx.x;
    if (i >= N) return;
    int r0 = rowptr[i], r1 = rowptr[i + 1];
    float4 a = ((const float4*)z2)[i];
    const float4* z = (const float4*)z2;
    int k = r0;
    for (; k + 8 <= r1; k += 8) {
        unsigned j[8];
        #pragma unroll
        for (int u = 0; u < 8; ++u) j[u] = csr[k + u];
        float4 v[8];
        #pragma unroll
        for (int u = 0; u < 8; ++u) v[u] = z[j[u]];
        #pragma unroll
        for (int u = 0; u < 8; ++u) {
            a.x += v[u].x; a.y += v[u].y; a.z += v[u].z; a.w += v[u].w;
        }
    }
    for (; k < r1; ++k) {
        float4 zv = z[csr[k]];
        a.x += zv.x; a.y += zv.y; a.z += zv.z; a.w += zv.w;
    }
    float di = dinv[i];
    float g0 = di * a.x, g1 = di * a.y, g2 = di * a.z, g3 = di * a.w;
    float h[4];
    #pragma unroll
    for (int c = 0; c < 4; ++c)
        h[c] = tanhf(b2[c] + g0 * W2[c] + g1 * W2[4 + c] + g2 * W2[8 + c] + g3 * W2[12 + c]);
    float v0 = h[0] * W3[0] + h[1] * W3[2] + h[2] * W3[4] + h[3] * W3[6];
    float v1 = h[0] * W3[1] + h[1] * W3[3] + h[2] * W3[5] + h[3] * W3[7];
    ((float2*)z3)[i] = make_float2(v0 * di, v1 * di);
}

__global__ void gcn3(const int* __restrict__ rowptr, const unsigned* __restrict__ csr,
                     const float* __restrict__ z3, const float* __restrict__ b3,
                     const float* __restrict__ dinv, float* __restrict__ out, int N) {
    int i = blockIdx.x * blockDim.x + threadIdx.x;
    if (i >= N) return;
    int r0 = rowptr[i], r1 = rowptr[i + 1];
    float2 zi = ((const float2*)z3)[i];
    float a0 = zi.x, a1 = zi.y;
    const float2* z = (const float2*)z3;
    int k = r0;
    for (; k + 16 <= r1; k += 16) {
        unsigned j[16];
        #pragma unroll
        for (int u = 0; u < 16; ++u) j[u] = csr[k + u];
        float2 v[16];
        #pragma unroll
        for (int u = 0; u < 16; ++u) v[u] = z[j[u]];
        #pragma unroll
        for (int u = 0; u < 16; ++u) { a0 += v[u].x; a1 += v[u].y; }
    }
    for (; k < r1; ++k) {
        float2 zv = z[csr[k]];
        a0 += zv.x; a1 += zv.y;
    }
    float di = dinv[i];
    ((float2*)out)[i] = make_float2(fmaf(di, a0, b3[0]), fmaf(di, a1, b3[1]));
}

extern "C" void kernel_launch(void* const* d_in, const int* in_sizes, int n_in,
                              void* d_out, int out_size, void* d_ws, size_t ws_size,
                              hipStream_t stream) {
    const float* x  = (const float*)d_in[0];
    const int*   ei = (const int*)d_in[1];
    const float* W1 = (const float*)d_in[2];
    const float* b1 = (const float*)d_in[3];
    const float* W2 = (const float*)d_in[4];
    const float* b2 = (const float*)d_in[5];
    const float* W3 = (const float*)d_in[6];
    const float* b3 = (const float*)d_in[7];
    float* out = (float*)d_out;

    const int N = in_sizes[0] / 2;
    const int E = in_sizes[1] / 2;
    const int* src = ei;
    const int* dst = ei + E;

    const int B = (N + NPB - 1) >> 12;               // 123 buckets
    const int ntiles = (E + T_TILE - 1) / T_TILE;    // 1954
    const int mlen = B * ntiles;                     // ~240K
    const int NB = (mlen + 1023) / 1024;             // <=1024
    const int SCAT_BLOCKS = 512;                     // 2/CU -> 2MB write set/XCD
    const int tilesPerBlk = (ntiles + SCAT_BLOCKS - 1) / SCAT_BLOCKS;

    // ws layout (256B-aligned). cntmat overlays z2 (z2 written only later by gcn1).
    auto align = [](size_t o) { return (o + 255) & ~(size_t)255; };
    char* base = (char*)d_ws;
    size_t off = 0;
    int*      rowptr = (int*)(base + off);      off = align(off + (size_t)(N + 1) * 4);
    float*    dinv   = (float*)(base + off);    off = align(off + (size_t)N * 4);
    float*    z1     = (float*)(base + off);    off = align(off + (size_t)2 * N * 4);
    float*    z2     = (float*)(base + off);    off = align(off + (size_t)4 * N * 4);
    float*    z3     = (float*)(base + off);    off = align(off + (size_t)2 * N * 4);
    int*      bsum   = (int*)(base + off);      off = align(off + (size_t)1024 * 4);
    unsigned* csr    = (unsigned*)(base + off); off = align(off + (size_t)E * 4);
    unsigned* pk32   = (unsigned*)(base + off); off = align(off + (size_t)E * 4);
    int*      cntmat = (int*)z2;                // overlay: 8MB >= mlen*4B

    dim3 blk(TPB);
    dim3 gN((N + TPB - 1) / TPB);

    tilecount<<<dim3(ntiles), blk, 0, stream>>>(dst, cntmat, ntiles, E, B);
    scan_k1<<<dim3(NB), blk, 0, stream>>>(cntmat, bsum, mlen);
    scan_k2<<<dim3(1), dim3(1024), 0, stream>>>(bsum, NB);
    scan_k3<<<dim3(NB), blk, 0, stream>>>(cntmat, bsum, mlen);
    bucketscatter<<<dim3(SCAT_BLOCKS), blk, 0, stream>>>(dst, src, cntmat, pk32,
                                                         ntiles, E, B, tilesPerBlk);
    bucketbuild<<<dim3(B), dim3(1024), 0, stream>>>(cntmat, pk32, ntiles, x, rowptr,
                                                    dinv, z1, csr, N, E, B);
    gcn1<<<gN, blk, 0, stream>>>(rowptr, csr, z1, W1, b1, dinv, z2, N);
    gcn2<<<gN, blk, 0, stream>>>(rowptr, csr, z2, W2, b2, W3, dinv, z3, N);
    gcn3<<<gN, blk, 0, stream>>>(rowptr, csr, z3, b3, dinv, out, N);
}